// Round 4
// baseline (668.028 us; speedup 1.0000x reference)
//
#include <hip/hip_runtime.h>

#define B_      16
#define CIN_    512
#define COUT_   3
#define WDIM_   512
#define HW4_    4096             // 128*128/4 float4 per plane
#define FC_GAIN     0.044194173824159216f   // 1/sqrt(512)
#define WEIGHT_GAIN 0.044194173824159216f   // 1/sqrt(512*1)
#define CLAMP_  256.0f

#define NGRP_   16               // channel groups (512/32)
#define CPG_    32               // channels per group
#define PC_     8                // float4 per thread per channel (pixel coarsening)
#define PART_OFF_ 131072         // float4 offset into d_ws for partials (2 MB)

typedef float v4f __attribute__((ext_vector_type(4)));

// Kernel 1: one wave per (b, c). Unchanged (L2-resident, ~8 us).
__global__ __launch_bounds__(64) void style_kernel(
    const float* __restrict__ w,
    const float* __restrict__ affine_W,
    const float* __restrict__ affine_b,
    const float* __restrict__ conv_w,
    float4* __restrict__ eff4) {
  const int bc   = blockIdx.x;        // 0 .. B*CIN-1
  const int b    = bc >> 9;
  const int c    = bc & 511;
  const int lane = threadIdx.x;

  const float* wb = w + b * WDIM_;
  const float* r1 = affine_W + (size_t)c * WDIM_;
  const float* r2 = affine_W + (size_t)(c + CIN_) * WDIM_;
  const float* r3 = affine_W + (size_t)(c + 2 * CIN_) * WDIM_;

  float p1 = 0.f, p2 = 0.f, p3 = 0.f;
#pragma unroll
  for (int j = 0; j < WDIM_ / 64; ++j) {
    const int k = j * 64 + lane;
    const float wk = wb[k];
    p1 = fmaf(wk, r1[k], p1);
    p2 = fmaf(wk, r2[k], p2);
    p3 = fmaf(wk, r3[k], p3);
  }
#pragma unroll
  for (int off = 32; off > 0; off >>= 1) {
    p1 += __shfl_down(p1, off);
    p2 += __shfl_down(p2, off);
    p3 += __shfl_down(p3, off);
  }
  if (lane == 0) {
    const float s1 = p1 * FC_GAIN + affine_b[c];
    const float s2 = p2 * FC_GAIN + affine_b[c + CIN_];
    const float s3 = p3 * FC_GAIN + affine_b[c + 2 * CIN_];
    const float style = (s1 * s2 + s3) * WEIGHT_GAIN;
    float4 e;
    e.x = conv_w[0 * CIN_ + c] * style;
    e.y = conv_w[1 * CIN_ + c] * style;
    e.z = conv_w[2 * CIN_ + c] * style;
    e.w = 0.f;
    eff4[bc] = e;
  }
}

#define FMA4(acc, xv, s)                                          \
  acc.x = fmaf(xv.x, (s), acc.x); acc.y = fmaf(xv.y, (s), acc.y); \
  acc.z = fmaf(xv.z, (s), acc.z); acc.w = fmaf(xv.w, (s), acc.w);

// Kernel 2a: channel-group partials with WAVE-CONTIGUOUS load sweeps.
// grid = 16 b * 2 tiles * 16 groups = 512 blocks of 256 (2 blocks/CU).
// Each wave owns 512 consecutive float4 (8 KB): per channel it issues 8
// back-to-back 1 KB loads covering one contiguous 8 KB run (unroll 2 ->
// 16 loads / 16 KB in flight). This is the only untested pattern axis:
// prior variants' consecutive wave loads jumped 64 KB (channel stride) or
// 4 KB; the 6.4 TB/s fill sweeps linearly. x loads NT (round-3 win);
// partial stores cached (50 MB, L3-resident for the reduce pass).
__global__ __launch_bounds__(256) void conv_partial_kernel(
    const float* __restrict__ x,
    const float4* __restrict__ eff4,
    float4* __restrict__ part) {
  __shared__ float4 s_eff[CPG_];

  const int bx   = blockIdx.x;       // b*32 + tile*16 + g
  const int b    = bx >> 5;          // 0..15
  const int tile = (bx >> 4) & 1;    // 0..1 (2048-float4 stripes)
  const int g    = bx & 15;          // 0..15
  const int tid  = threadIdx.x;
  const int wave = tid >> 6;         // 0..3
  const int lane = tid & 63;

  if (tid < CPG_) s_eff[tid] = eff4[b * CIN_ + g * CPG_ + tid];
  __syncthreads();

  // wave base: contiguous 512-float4 (8 KB) run inside this plane stripe
  const size_t pix = (size_t)tile * 2048 + (size_t)wave * 512 + lane;
  const v4f* xb = (const v4f*)x + ((size_t)b * CIN_ + (size_t)g * CPG_) * HW4_ + pix;

  v4f a0[PC_], a1[PC_], a2[PC_];
#pragma unroll
  for (int k = 0; k < PC_; ++k) {
    a0[k] = (v4f){0.f, 0.f, 0.f, 0.f};
    a1[k] = (v4f){0.f, 0.f, 0.f, 0.f};
    a2[k] = (v4f){0.f, 0.f, 0.f, 0.f};
  }

#pragma unroll 2
  for (int c = 0; c < CPG_; ++c) {
    v4f xv[PC_];
#pragma unroll
    for (int k = 0; k < PC_; ++k)
      xv[k] = __builtin_nontemporal_load(&xb[(size_t)c * HW4_ + k * 64]);
    const float4 e = s_eff[c];
#pragma unroll
    for (int k = 0; k < PC_; ++k) {
      FMA4(a0[k], xv[k], e.x);
      FMA4(a1[k], xv[k], e.y);
      FMA4(a2[k], xv[k], e.z);
    }
  }

  // part layout: [(b*16+g)*3 + o][pix], cached stores (L3-resident)
  v4f* pb = (v4f*)part + ((size_t)(b * NGRP_ + g) * COUT_) * HW4_ + pix;
#pragma unroll
  for (int k = 0; k < PC_; ++k) {
    pb[k * 64]             = a0[k];
    pb[k * 64 + HW4_]      = a1[k];
    pb[k * 64 + 2 * HW4_]  = a2[k];
  }
}

// Kernel 2b: sum the 16 group-partials, add bias, clamp, store (NT).
// grid = 16 b * 3 o * 4 tiles = 192 blocks of 256. Reads 48 MB (L3), writes 3 MB.
__global__ __launch_bounds__(256) void reduce_kernel(
    const float4* __restrict__ part,
    const float* __restrict__ conv_b,
    float* __restrict__ out) {
  const int bx   = blockIdx.x;      // b*12 + o*4 + tile
  const int b    = bx / 12;
  const int r    = bx % 12;
  const int o    = r >> 2;
  const int tile = r & 3;
  const int tid  = threadIdx.x;

  v4f acc[4];
#pragma unroll
  for (int k = 0; k < 4; ++k) acc[k] = (v4f){0.f, 0.f, 0.f, 0.f};

  for (int g = 0; g < NGRP_; ++g) {
    const v4f* pp = (const v4f*)part
        + ((size_t)(b * NGRP_ + g) * COUT_ + o) * HW4_
        + (size_t)tile * 1024 + tid;
#pragma unroll
    for (int k = 0; k < 4; ++k) {
      const v4f v = pp[k * 256];
      acc[k].x += v.x; acc[k].y += v.y; acc[k].z += v.z; acc[k].w += v.w;
    }
  }

  const float bb = conv_b[o];
#define CLMP(v) fminf(fmaxf((v) + bb, -CLAMP_), CLAMP_)
  v4f* op = (v4f*)out + ((size_t)b * COUT_ + o) * HW4_ + (size_t)tile * 1024 + tid;
#pragma unroll
  for (int k = 0; k < 4; ++k) {
    v4f res = { CLMP(acc[k].x), CLMP(acc[k].y), CLMP(acc[k].z), CLMP(acc[k].w) };
    __builtin_nontemporal_store(res, &op[k * 256]);
  }
#undef CLMP
}

extern "C" void kernel_launch(void* const* d_in, const int* in_sizes, int n_in,
                              void* d_out, int out_size, void* d_ws, size_t ws_size,
                              hipStream_t stream) {
  const float* x        = (const float*)d_in[0];  // [16,512,128,128]
  const float* w        = (const float*)d_in[1];  // [16,512]
  const float* affine_W = (const float*)d_in[2];  // [1536,512]
  const float* affine_b = (const float*)d_in[3];  // [1536]
  const float* conv_w   = (const float*)d_in[4];  // [3,512]
  const float* conv_b   = (const float*)d_in[5];  // [3]
  float* out = (float*)d_out;                     // [16,3,128,128]

  float4* eff4 = (float4*)d_ws;                   // [0, 128 KB)
  float4* part = (float4*)d_ws + PART_OFF_;       // [2 MB, 2 MB + 50.3 MB)

  style_kernel<<<B_ * CIN_, 64, 0, stream>>>(w, affine_W, affine_b, conv_w, eff4);
  conv_partial_kernel<<<B_ * 2 * NGRP_, 256, 0, stream>>>(x, eff4, part);
  reduce_kernel<<<B_ * COUT_ * 4, 256, 0, stream>>>(part, conv_b, out);
}